// Round 4
// baseline (28169.485 us; speedup 1.0000x reference)
//
#include <hip/hip_runtime.h>
#include <cstddef>

// ---------------- problem constants ----------------
constexpr int BSz = 8;     // batch
constexpr int Bb  = 8;     // blocks (episodic banks)
constexpr int Mm  = 512;   // memory slots
constexpr int Dd  = 128;   // feature dim
constexpr int Nn  = 1024;  // tokens
constexpr int NT  = 16;    // n-rows per workgroup (k1/k2a)
constexpr int MT  = 32;    // m-tile staged in LDS (f32)
constexpr float NEGV = -1e30f;

__device__ __forceinline__ float softplusf(float x) {
    return (x > 20.f) ? x : log1pf(expf(x));
}
__device__ __forceinline__ float dot4(float4 a, float4 b) {
    return a.x * b.x + a.y * b.y + a.z * b.z + a.w * b.w;
}

// LDS reduction over each aligned group of 16 threads (all 256 threads must call)
__device__ __forceinline__ float red16_sum(float* red, int tid, float v) {
    red[tid] = v; __syncthreads();
    float r = 0.f; int base = tid & ~15;
    #pragma unroll
    for (int j = 0; j < 16; ++j) r += red[base + j];
    __syncthreads();
    return r;
}
__device__ __forceinline__ float red16_max(float* red, int tid, float v) {
    red[tid] = v; __syncthreads();
    float r = NEGV; int base = tid & ~15;
    #pragma unroll
    for (int j = 0; j < 16; ++j) r = fmaxf(r, red[base + j]);
    __syncthreads();
    return r;
}

// =====================================================================
// Kernel 1: 2-step iterative attention -> y_em
// grid (N/NT, B, BS), block 256.  Thread map: nr = tid>>4 (row), q = tid&15.
// =====================================================================
__global__ __launch_bounds__(256) void k1_attn(
    const float* __restrict__ seed, const float* __restrict__ emK, const float* __restrict__ emV,
    const float* __restrict__ emS, const float* __restrict__ w1, const float* __restrict__ w2,
    const float* __restrict__ gb, const float* __restrict__ rtau, float* __restrict__ y_em)
{
    const int bs = blockIdx.z, b = blockIdx.y, n0 = blockIdx.x * NT;
    const int tid = threadIdx.x;
    const int nr = tid >> 4, q = tid & 15;

    __shared__ float sh_y[NT][Dd];          // evolving y tile
    __shared__ float sh_sc[NT][Mm];         // scores / attn
    __shared__ float sh_t[MT][Dd + 4];      // staged K or V tile (f32)
    __shared__ float sh_w1[Dd], sh_w2[Dd], sh_gb[Dd];
    __shared__ float sh_act[Mm];
    __shared__ float sh_has;
    __shared__ float sh_red[256];

    const float tau  = softplusf(rtau[b]) + 0.1f;
    const float itau = 1.0f / tau;
    const size_t pair = (size_t)(bs * Bb + b);

    if (tid == 0) sh_has = 0.f;
    if (tid < Dd) {
        sh_w1[tid] = w1[b * Dd + tid];
        sh_w2[tid] = w2[b * Dd + tid];
        sh_gb[tid] = gb[b * Dd + tid];
    }
    __syncthreads();
    for (int m = tid; m < Mm; m += 256) {
        float a = (emS[pair * Mm + m] > 0.f) ? 1.f : 0.f;
        sh_act[m] = a;
        if (a != 0.f) sh_has = 1.f;          // benign same-value race
    }
    {
        const float4* s4 = (const float4*)(seed + ((size_t)bs * Nn + n0) * Dd);
        for (int i = tid; i < NT * Dd / 4; i += 256) {   // 512 chunks
            int n = i >> 5, c = i & 31;
            *(float4*)&sh_y[n][c * 4] = s4[i];
        }
    }
    __syncthreads();
    const float has = sh_has;
    const float* Kb = emK + pair * Mm * Dd;
    const float* Vb = emV + pair * Mm * Dd;

    for (int step = 0; step < 2; ++step) {
        // ---- scores = (y . K^T)/tau ----
        for (int mt = 0; mt < Mm / MT; ++mt) {           // 16 tiles
            const float4* Ks = (const float4*)(Kb + (size_t)mt * MT * Dd);
            for (int i = tid; i < MT * Dd / 4; i += 256) {  // 1024 chunks
                int m = i >> 5, c = i & 31;
                *(float4*)&sh_t[m][c * 4] = Ks[i];
            }
            __syncthreads();
            float acc[2] = {0.f, 0.f};
            for (int c = 0; c < 32; ++c) {
                float4 yv = *(const float4*)&sh_y[nr][c * 4];
                #pragma unroll
                for (int j = 0; j < 2; ++j) {
                    float4 kv = *(const float4*)&sh_t[q * 2 + j][c * 4];
                    acc[j] += dot4(yv, kv);
                }
            }
            #pragma unroll
            for (int j = 0; j < 2; ++j) sh_sc[nr][mt * MT + q * 2 + j] = acc[j] * itau;
            __syncthreads();
        }
        // ---- masked softmax per row (16 threads/row, 32 m each) ----
        {
            float mxp = NEGV;
            for (int k = 0; k < 32; ++k) {
                int m = q * 32 + k;
                float v = (sh_act[m] != 0.f) ? sh_sc[nr][m] : NEGV;
                mxp = fmaxf(mxp, v);
            }
            float mx = red16_max(sh_red, tid, mxp);
            float sump = 0.f;
            for (int k = 0; k < 32; ++k) {
                int m = q * 32 + k;
                float v = (sh_act[m] != 0.f) ? sh_sc[nr][m] : NEGV;
                float e = expf(v - mx);      // NEG-NEG=0 -> uniform fallback preserved
                sh_sc[nr][m] = e;
                sump += e;
            }
            float sum = red16_sum(sh_red, tid, sump);
            float sc_ = has / sum;
            for (int k = 0; k < 32; ++k) sh_sc[nr][q * 32 + k] *= sc_;
        }
        __syncthreads();
        // ---- delta = attn @ V ----  thread (nr, q) owns d = q*8 .. q*8+7
        float dacc[8] = {0.f, 0.f, 0.f, 0.f, 0.f, 0.f, 0.f, 0.f};
        for (int mt = 0; mt < Mm / MT; ++mt) {
            const float4* Vs = (const float4*)(Vb + (size_t)mt * MT * Dd);
            for (int i = tid; i < MT * Dd / 4; i += 256) {
                int m = i >> 5, c = i & 31;
                *(float4*)&sh_t[m][c * 4] = Vs[i];
            }
            __syncthreads();
            for (int m = 0; m < MT; ++m) {
                float a = sh_sc[nr][mt * MT + m];
                float4 v0 = *(const float4*)&sh_t[m][q * 8];
                float4 v1 = *(const float4*)&sh_t[m][q * 8 + 4];
                dacc[0] += a * v0.x; dacc[1] += a * v0.y;
                dacc[2] += a * v0.z; dacc[3] += a * v0.w;
                dacc[4] += a * v1.x; dacc[5] += a * v1.y;
                dacc[6] += a * v1.z; dacc[7] += a * v1.w;
            }
            __syncthreads();
        }
        // ---- gate + y update ----
        {
            int d0 = q * 8;
            #pragma unroll
            for (int e = 0; e < 8; ++e) {
                int d = d0 + e;
                float yv = sh_y[nr][d], dl = dacc[e];
                float z = sh_w1[d] * yv + sh_w2[d] * dl + sh_gb[d];
                float g = 1.f / (1.f + expf(-z));
                sh_y[nr][d] = yv + g * dl;
            }
        }
        __syncthreads();
    }
    // ---- y_em[bs,n,b,:] = y - seed ----
    {
        int d0 = q * 8;
        const float* sr = seed + ((size_t)bs * Nn + n0 + nr) * Dd + d0;
        float4 s0 = *(const float4*)sr;
        float4 s1 = *(const float4*)(sr + 4);
        float* yo = y_em + (((size_t)bs * Nn + n0 + nr) * Bb + b) * Dd + d0;
        float4 o0, o1;
        o0.x = sh_y[nr][d0 + 0] - s0.x; o0.y = sh_y[nr][d0 + 1] - s0.y;
        o0.z = sh_y[nr][d0 + 2] - s0.z; o0.w = sh_y[nr][d0 + 3] - s0.w;
        o1.x = sh_y[nr][d0 + 4] - s1.x; o1.y = sh_y[nr][d0 + 5] - s1.y;
        o1.z = sh_y[nr][d0 + 6] - s1.z; o1.w = sh_y[nr][d0 + 7] - s1.w;
        *(float4*)yo = o0;
        *(float4*)(yo + 4) = o1;
    }
}

// =====================================================================
// Kernel 2a: novelty path -> delta_em + per-n stats {nov, rmax, rsum}
// Stats stored as f32 in the TAIL of this pair's new_V region (slots 448+),
// which is only overwritten later by the tile-7 k2b launch (after its last read).
// =====================================================================
__global__ __launch_bounds__(256) void k2a_nov(
    const float* __restrict__ w_cand, const float* __restrict__ surprise,
    const float* __restrict__ emK, const float* __restrict__ emV, const float* __restrict__ emS,
    const float* __restrict__ rtau, const float* __restrict__ rtauw,
    float* __restrict__ delta_em, float* newV /* stats alias - no restrict */)
{
    const int bs = blockIdx.z, b = blockIdx.y, n0 = blockIdx.x * NT;
    const int tid = threadIdx.x;
    const int nr = tid >> 4, q = tid & 15;

    __shared__ float sh_y[NT][Dd];     // w_norm tile
    __shared__ float sh_sc[NT][Mm];    // raw scores -> nov_attn
    __shared__ float sh_t[MT][Dd + 4];
    __shared__ float sh_act[Mm];
    __shared__ float sh_has;
    __shared__ float sh_red[256];

    const float tau  = softplusf(rtau[b])  + 0.1f;
    const float tauw = softplusf(rtauw[b]) + 0.1f;
    const float itau = 1.f / tau, itw = 1.f / tauw;
    const size_t pair = (size_t)(bs * Bb + b);
    float* stats = newV + pair * (size_t)(Mm * Dd) + 448 * Dd;  // 8192 f32 capacity, use 3072

    if (tid == 0) sh_has = 0.f;
    __syncthreads();
    for (int m = tid; m < Mm; m += 256) {
        float a = (emS[pair * Mm + m] > 0.f) ? 1.f : 0.f;
        sh_act[m] = a;
        if (a != 0.f) sh_has = 1.f;
    }
    {
        const float4* s4 = (const float4*)(w_cand + ((size_t)bs * Nn + n0) * Dd);
        for (int i = tid; i < NT * Dd / 4; i += 256) {
            int n = i >> 5, c = i & 31;
            *(float4*)&sh_y[n][c * 4] = s4[i];
        }
    }
    __syncthreads();
    const float has = sh_has;
    // normalize rows -> w_norm
    {
        float p = 0.f;
        #pragma unroll
        for (int e = 0; e < 8; ++e) { float v = sh_y[nr][q * 8 + e]; p += v * v; }
        p = red16_sum(sh_red, tid, p);
        float inv = 1.f / fmaxf(sqrtf(p), 1e-12f);
        #pragma unroll
        for (int e = 0; e < 8; ++e) sh_y[nr][q * 8 + e] *= inv;
    }
    __syncthreads();
    const float* Kb = emK + pair * Mm * Dd;
    const float* Vb = emV + pair * Mm * Dd;

    // ---- raw = w_norm . K^T ----
    for (int mt = 0; mt < Mm / MT; ++mt) {
        const float4* Ks = (const float4*)(Kb + (size_t)mt * MT * Dd);
        for (int i = tid; i < MT * Dd / 4; i += 256) {
            int m = i >> 5, c = i & 31;
            *(float4*)&sh_t[m][c * 4] = Ks[i];
        }
        __syncthreads();
        float acc[2] = {0.f, 0.f};
        for (int c = 0; c < 32; ++c) {
            float4 yv = *(const float4*)&sh_y[nr][c * 4];
            #pragma unroll
            for (int j = 0; j < 2; ++j) {
                float4 kv = *(const float4*)&sh_t[q * 2 + j][c * 4];
                acc[j] += dot4(yv, kv);
            }
        }
        #pragma unroll
        for (int j = 0; j < 2; ++j) sh_sc[nr][mt * MT + q * 2 + j] = acc[j];   // raw dot
        __syncthreads();
    }
    // ---- both softmax stats; sh_sc <- nov_attn; route stats -> out-tail ----
    {
        float mx1p = NEGV, mx2p = NEGV;
        for (int k = 0; k < 32; ++k) {
            int m = q * 32 + k;
            float raw = sh_sc[nr][m];
            bool a = (sh_act[m] != 0.f);
            mx1p = fmaxf(mx1p, a ? raw * itau : NEGV);
            mx2p = fmaxf(mx2p, a ? raw * itw  : NEGV);
        }
        float mx1 = red16_max(sh_red, tid, mx1p);
        float mx2 = red16_max(sh_red, tid, mx2p);
        float s1p = 0.f, s2p = 0.f;
        for (int k = 0; k < 32; ++k) {
            int m = q * 32 + k;
            float raw = sh_sc[nr][m];
            bool a = (sh_act[m] != 0.f);
            float v1 = a ? raw * itau : NEGV;
            float v2 = a ? raw * itw  : NEGV;
            float e1 = expf(v1 - mx1);
            s1p += e1;
            s2p += expf(v2 - mx2);
            sh_sc[nr][m] = e1;
        }
        float s1 = red16_sum(sh_red, tid, s1p);
        float s2 = red16_sum(sh_red, tid, s2p);
        float sc_ = has / s1;
        for (int k = 0; k < 32; ++k) sh_sc[nr][q * 32 + k] *= sc_;
        if (q == 0) {
            stats[1024 + n0 + nr] = mx2;
            stats[2048 + n0 + nr] = s2;
        }
    }
    __syncthreads();
    // ---- recon = nov_attn @ V ----
    float racc[8] = {0.f, 0.f, 0.f, 0.f, 0.f, 0.f, 0.f, 0.f};
    for (int mt = 0; mt < Mm / MT; ++mt) {
        const float4* Vs = (const float4*)(Vb + (size_t)mt * MT * Dd);
        for (int i = tid; i < MT * Dd / 4; i += 256) {
            int m = i >> 5, c = i & 31;
            *(float4*)&sh_t[m][c * 4] = Vs[i];
        }
        __syncthreads();
        for (int m = 0; m < MT; ++m) {
            float a = sh_sc[nr][mt * MT + m];
            float4 v0 = *(const float4*)&sh_t[m][q * 8];
            float4 v1 = *(const float4*)&sh_t[m][q * 8 + 4];
            racc[0] += a * v0.x; racc[1] += a * v0.y;
            racc[2] += a * v0.z; racc[3] += a * v0.w;
            racc[4] += a * v1.x; racc[5] += a * v1.y;
            racc[6] += a * v1.z; racc[7] += a * v1.w;
        }
        __syncthreads();
    }
    // ---- novelty + delta_em ----
    {
        int d0 = q * 8;
        const float* wr = w_cand + ((size_t)bs * Nn + n0 + nr) * Dd + d0;
        float4 w0 = *(const float4*)wr;
        float4 w1_ = *(const float4*)(wr + 4);
        float wc[8] = {w0.x, w0.y, w0.z, w0.w, w1_.x, w1_.y, w1_.z, w1_.w};
        float pe = 0.f;
        #pragma unroll
        for (int e = 0; e < 8; ++e) { float df = wc[e] - racc[e]; pe += df * df; }
        pe = red16_sum(sh_red, tid, pe);
        const float* sp = surprise + ((size_t)bs * Nn + n0 + nr) * Dd + d0;
        float4 u0 = *(const float4*)sp;
        float4 u1 = *(const float4*)(sp + 4);
        float ps = dot4(u0, u0) + dot4(u1, u1);
        ps = red16_sum(sh_red, tid, ps);
        float novl = 0.5f * sqrtf(ps) + 0.5f * sqrtf(pe);
        if (q == 0) stats[n0 + nr] = novl;
        float* dout = delta_em + (((size_t)bs * Nn + n0 + nr) * Bb + b) * Dd + d0;
        float4 o0, o1;
        o0.x = novl * wc[0]; o0.y = novl * wc[1]; o0.z = novl * wc[2]; o0.w = novl * wc[3];
        o1.x = novl * wc[4]; o1.y = novl * wc[5]; o1.z = novl * wc[6]; o1.w = novl * wc[7];
        *(float4*)dout = o0;
        *(float4*)(dout + 4) = o1;
    }
}

// =====================================================================
// Kernel 2b: route recompute + update_K/V + new_K/V/age + S_pre (into newS)
// grid (#mtiles, B, BS), block 256.  Thread: ml = tid>>2 (m), dq = tid&3.
// Launched twice: mt_base=0 gridDim.x=7 (slots 0..447), then mt_base=7
// gridDim.x=1 (slots 448..511 — overwrites the stats region in its epilogue,
// safe: last stats read precedes the epilogue via loop-final __syncthreads()).
// =====================================================================
__global__ __launch_bounds__(256) void k2b_upd(
    const float* __restrict__ w_cand, const float* __restrict__ emK, const float* __restrict__ emV,
    const float* __restrict__ emS, const float* __restrict__ emAge,
    const float* __restrict__ g_em, const float* __restrict__ rtauw,
    float* __restrict__ newK, float* newV /* aliases stats - no restrict */,
    float* __restrict__ newAge, float* __restrict__ newS, int mt_base)
{
    const int bs = blockIdx.z, b = blockIdx.y, mt = mt_base + blockIdx.x;
    const int m0 = mt * 64;
    const int tid = threadIdx.x;
    const int ml = tid >> 2, dq = tid & 3, d0 = dq * 32;

    __shared__ float sh_wn[16][Dd];                 // w_norm tile
    __shared__ float sh_nv[16], sh_rm[16], sh_rs[16], sh_nrm[16];
    __shared__ float sh_red[256];

    const float tauw = softplusf(rtauw[b]) + 0.1f;
    const float itw = 1.f / tauw;
    const float gv = g_em[bs * Bb + b];
    const size_t pair = (size_t)(bs * Bb + b);
    const float* stats = newV + pair * (size_t)(Mm * Dd) + 448 * Dd;
    const float actm = (emS[pair * Mm + m0 + ml] > 0.f) ? 1.f : 0.f;

    // hoist this thread's K chunk (row m0+ml, d0..d0+31) into registers
    float kreg[32];
    {
        const float* Kr = emK + (pair * Mm + m0 + ml) * (size_t)Dd + d0;
        #pragma unroll
        for (int c = 0; c < 8; ++c) {
            float4 kv = *(const float4*)(Kr + c * 4);
            kreg[c * 4 + 0] = kv.x; kreg[c * 4 + 1] = kv.y;
            kreg[c * 4 + 2] = kv.z; kreg[c * 4 + 3] = kv.w;
        }
    }
    float uK[32], uV[32];
    #pragma unroll
    for (int j = 0; j < 32; ++j) { uK[j] = 0.f; uV[j] = 0.f; }
    float den = 0.f;

    for (int nt = 0; nt < Nn / 16; ++nt) {
        int nb = nt * 16;
        // stage w_cand tile (f32)
        {
            const float4* s4 = (const float4*)(w_cand + ((size_t)bs * Nn + nb) * Dd);
            for (int i = tid; i < 16 * Dd / 4; i += 256) {  // 512 chunks
                int n = i >> 5, c = i & 31;
                *(float4*)&sh_wn[n][c * 4] = s4[i];
            }
        }
        if (tid < 16) {
            sh_nv[tid] = stats[nb + tid];
            sh_rm[tid] = stats[1024 + nb + tid];
            sh_rs[tid] = stats[2048 + nb + tid];
        }
        __syncthreads();
        // normalize rows; keep norm (w_cand = w_norm * nrm)
        {
            int n = tid >> 4, qq = tid & 15;
            float p = 0.f;
            #pragma unroll
            for (int e = 0; e < 8; ++e) { float v = sh_wn[n][qq * 8 + e]; p += v * v; }
            p = red16_sum(sh_red, tid, p);
            float nrm = fmaxf(sqrtf(p), 1e-12f);
            float inv = 1.f / nrm;
            if (qq == 0) sh_nrm[n] = nrm;
            #pragma unroll
            for (int e = 0; e < 8; ++e) sh_wn[n][qq * 8 + e] *= inv;
        }
        __syncthreads();
        for (int nl = 0; nl < 16; ++nl) {
            const float* wn = &sh_wn[nl][d0];
            float p = 0.f;
            #pragma unroll
            for (int j = 0; j < 32; ++j) p += kreg[j] * wn[j];
            p += __shfl_xor(p, 1, 4);
            p += __shfl_xor(p, 2, 4);
            float val = (actm != 0.f) ? p * itw : NEGV;
            float wr = sh_nv[nl] * expf(val - sh_rm[nl]) / sh_rs[nl];
            den += wr;
            float wrv = wr * sh_nrm[nl];
            #pragma unroll
            for (int j = 0; j < 32; ++j) {
                float w = wn[j];
                uK[j] += wr * w;      // update_K accum (w_norm)
                uV[j] += wrv * w;     // update_V accum (w_cand = w_norm*nrm)
            }
        }
        __syncthreads();
    }
    // ---- finalize ----
    float invd = 1.f / fmaxf(den, 1e-8f);
    float ragg = den * (1.f / (float)Nn);
    float alpha = fminf(gv * ragg, 1.f);
    float oma = 1.f - alpha;
    float p = 0.f;
    #pragma unroll
    for (int j = 0; j < 32; ++j) { float u = uK[j] * invd; uK[j] = u; p += u * u; }
    p += __shfl_xor(p, 1, 4);
    p += __shfl_xor(p, 2, 4);
    float invn = 1.f / fmaxf(sqrtf(p), 1e-12f);

    float* Ko = newK + (pair * Mm + m0 + ml) * (size_t)Dd + d0;
    float* Vo = newV + (pair * Mm + m0 + ml) * (size_t)Dd + d0;
    const float* Vr = emV + (pair * Mm + m0 + ml) * (size_t)Dd + d0;
    #pragma unroll
    for (int c = 0; c < 8; ++c) {
        float4 ov;
        ov.x = oma * kreg[c * 4 + 0] + alpha * uK[c * 4 + 0] * invn;
        ov.y = oma * kreg[c * 4 + 1] + alpha * uK[c * 4 + 1] * invn;
        ov.z = oma * kreg[c * 4 + 2] + alpha * uK[c * 4 + 2] * invn;
        ov.w = oma * kreg[c * 4 + 3] + alpha * uK[c * 4 + 3] * invn;
        *(float4*)(Ko + c * 4) = ov;
    }
    #pragma unroll
    for (int c = 0; c < 8; ++c) {
        float4 vv = *(const float4*)(Vr + c * 4);
        float4 ov;
        ov.x = oma * vv.x + alpha * uV[c * 4 + 0] * invd;
        ov.y = oma * vv.y + alpha * uV[c * 4 + 1] * invd;
        ov.z = oma * vv.z + alpha * uV[c * 4 + 2] * invd;
        ov.w = oma * vv.w + alpha * uV[c * 4 + 3] * invd;
        *(float4*)(Vo + c * 4) = ov;
    }
    if (dq == 0) {
        float S = emS[pair * Mm + m0 + ml];
        float Sp = fminf(fmaxf(S + alpha, 0.f), 3.0f);
        newS[pair * Mm + m0 + ml] = Sp;                // pre-rescale value
        float age = emAge[pair * Mm + m0 + ml];
        newAge[pair * Mm + m0 + ml] = age * oma;
    }
}

// =====================================================================
// Kernel 2c: budget rescale of new_S in place (f32)
// grid 64 (one WG per pair), block 256
// =====================================================================
__global__ __launch_bounds__(256) void k2c_scale(float* newS)
{
    const int p = blockIdx.x, tid = threadIdx.x;
    __shared__ float red[256];
    float v0 = newS[(size_t)p * Mm + tid];
    float v1 = newS[(size_t)p * Mm + 256 + tid];
    red[tid] = v0 + v1;
    __syncthreads();
    for (int s = 128; s > 0; s >>= 1) {
        if (tid < s) red[tid] += red[tid + s];
        __syncthreads();
    }
    float tot = red[0];
    float sc = fminf(1.f, 32.0f / fmaxf(tot, 1e-8f));
    newS[(size_t)p * Mm + tid]       = v0 * sc;
    newS[(size_t)p * Mm + 256 + tid] = v1 * sc;
}

// =====================================================================
extern "C" void kernel_launch(void* const* d_in, const int* in_sizes, int n_in,
                              void* d_out, int out_size, void* d_ws, size_t ws_size,
                              hipStream_t stream)
{
    const float* seed     = (const float*)d_in[0];
    const float* w_cand   = (const float*)d_in[1];
    const float* surprise = (const float*)d_in[2];
    const float* g_em     = (const float*)d_in[3];
    const float* emK      = (const float*)d_in[4];
    const float* emV      = (const float*)d_in[5];
    const float* emS      = (const float*)d_in[6];
    const float* emAge    = (const float*)d_in[7];
    const float* w1       = (const float*)d_in[8];
    const float* w2       = (const float*)d_in[9];
    const float* gb       = (const float*)d_in[10];
    const float* rtau     = (const float*)d_in[11];
    const float* rtauw    = (const float*)d_in[12];

    float* out = (float*)d_out;
    float* y_em     = out;                            // (BS,N,B,D)  8388608
    float* delta_em = out + (size_t)8388608;          // (BS,N,B,D)  8388608
    float* newK     = out + (size_t)16777216;         // (BS,B,M,D)  4194304
    float* newV     = out + (size_t)20971520;         // (BS,B,M,D)  4194304
    float* newS     = out + (size_t)25165824;         // (BS,B,M)    32768
    float* newAge   = out + (size_t)25198592;         // (BS,B,M)    32768
    (void)d_ws; (void)ws_size;                        // workspace unused

    dim3 blk(256);
    dim3 g1(Nn / NT, Bb, BSz);          // 64 x 8 x 8
    k1_attn<<<g1, blk, 0, stream>>>(seed, emK, emV, emS, w1, w2, gb, rtau, y_em);
    k2a_nov<<<g1, blk, 0, stream>>>(w_cand, surprise, emK, emV, emS, rtau, rtauw,
                                    delta_em, newV);
    // m-tiles 0..6 (do not touch stats tail), then tile 7 (owns/retires stats)
    k2b_upd<<<dim3(7, Bb, BSz), blk, 0, stream>>>(w_cand, emK, emV, emS, emAge, g_em, rtauw,
                                                  newK, newV, newAge, newS, 0);
    k2b_upd<<<dim3(1, Bb, BSz), blk, 0, stream>>>(w_cand, emK, emV, emS, emAge, g_em, rtauw,
                                                  newK, newV, newAge, newS, 7);
    k2c_scale<<<dim3(64), blk, 0, stream>>>(newS);
}

// Round 5
// 5438.650 us; speedup vs baseline: 5.1795x; 5.1795x over previous
//
#include <hip/hip_runtime.h>
#include <cstddef>

// ---------------- problem constants ----------------
constexpr int BSz = 8;     // batch
constexpr int Bb  = 8;     // blocks (episodic banks)
constexpr int Mm  = 512;   // memory slots
constexpr int Dd  = 128;   // feature dim
constexpr int Nn  = 1024;  // tokens
constexpr float NEGV = -1e30f;

__device__ __forceinline__ float softplusf(float x) {
    return (x > 20.f) ? x : log1pf(expf(x));
}
__device__ __forceinline__ float dot4(float4 a, float4 b) {
    return a.x * b.x + a.y * b.y + a.z * b.z + a.w * b.w;
}
__device__ __forceinline__ float wred_sum(float v) {
    #pragma unroll
    for (int off = 32; off >= 1; off >>= 1) v += __shfl_xor(v, off);
    return v;
}
__device__ __forceinline__ float wred_max(float v) {
    #pragma unroll
    for (int off = 32; off >= 1; off >>= 1) v = fmaxf(v, __shfl_xor(v, off));
    return v;
}

// stage a 64-row x 128-col f32 tile into LDS [64][132] (conflict-free granules)
__device__ __forceinline__ void stage_tile(const float* __restrict__ src,
                                           float (*sh)[132], int tid) {
    const float4* s4 = (const float4*)src;
    #pragma unroll
    for (int it = 0; it < 8; ++it) {
        int i = tid + it * 256;
        int row = i >> 5, c = i & 31;
        *(float4*)&sh[row][c * 4] = s4[i];
    }
}

// =====================================================================
// Kernel 1: 2-step iterative attention -> y_em
// grid (Nn/32, Bb, BSz) = (32,8,8), block 256 = 4 waves.
// Wave w owns rows R..R+7; lane l owns m = t*64+l (scores) / d = 2l,2l+1.
// =====================================================================
__global__ __launch_bounds__(256) void k1_attn(
    const float* __restrict__ seed, const float* __restrict__ emK, const float* __restrict__ emV,
    const float* __restrict__ emS, const float* __restrict__ w1, const float* __restrict__ w2,
    const float* __restrict__ gb, const float* __restrict__ rtau, float* __restrict__ y_em)
{
    const int bs = blockIdx.z, b = blockIdx.y, n0 = blockIdx.x * 32;
    const int tid = threadIdx.x;
    const int wv = tid >> 6, l = tid & 63;
    const int R = wv * 8;

    __shared__ float sh_y[32][Dd];        // 16 KB evolving y
    __shared__ float sh_t[64][132];       // 33.8 KB K/V tile
    __shared__ float sh_a[32][64];        // 8 KB attn tile
    __shared__ float sh_w1[Dd], sh_w2[Dd], sh_gb[Dd];

    const float tau  = softplusf(rtau[b]) + 0.1f;
    const float itau = 1.0f / tau;
    const size_t pair = (size_t)(bs * Bb + b);

    if (tid < Dd) {
        sh_w1[tid] = w1[b * Dd + tid];
        sh_w2[tid] = w2[b * Dd + tid];
        sh_gb[tid] = gb[b * Dd + tid];
    }
    // activity mask: lane l covers m = t*64+l
    float am[8]; bool anyact = false;
    #pragma unroll
    for (int t = 0; t < 8; ++t) {
        float s = emS[pair * Mm + t * 64 + l];
        am[t] = (s > 0.f) ? 1.f : 0.f;
        anyact = anyact || (s > 0.f);
    }
    const float has = __ballot(anyact) ? 1.f : 0.f;
    // stage y = seed tile
    {
        const float4* s4 = (const float4*)(seed + ((size_t)bs * Nn + n0) * Dd);
        #pragma unroll
        for (int it = 0; it < 4; ++it) {
            int i = tid + it * 256;
            int row = i >> 5, c = i & 31;
            *(float4*)&sh_y[row][c * 4] = s4[i];
        }
    }
    __syncthreads();
    const float wA = sh_w1[2 * l], wA1 = sh_w1[2 * l + 1];
    const float wB = sh_w2[2 * l], wB1 = sh_w2[2 * l + 1];
    const float gB = sh_gb[2 * l], gB1 = sh_gb[2 * l + 1];

    const float* Kb = emK + pair * Mm * Dd;
    const float* Vb = emV + pair * Mm * Dd;

    for (int step = 0; step < 2; ++step) {
        // ---- scores: sc[r][t] = y[R+r] . K[t*64+l] * itau ----
        float sc[8][8];
        for (int t = 0; t < 8; ++t) {
            stage_tile(Kb + (size_t)t * 64 * Dd, sh_t, tid);
            __syncthreads();
            float acc[8] = {0.f,0.f,0.f,0.f,0.f,0.f,0.f,0.f};
            for (int c4 = 0; c4 < 32; ++c4) {
                float4 kv = *(const float4*)&sh_t[l][c4 * 4];
                #pragma unroll
                for (int r = 0; r < 8; ++r) {
                    float4 yv = *(const float4*)&sh_y[R + r][c4 * 4];  // broadcast
                    acc[r] += dot4(yv, kv);
                }
            }
            #pragma unroll
            for (int r = 0; r < 8; ++r) sc[r][t] = acc[r] * itau;
            __syncthreads();
        }
        // ---- masked softmax per row (full-wave reductions) ----
        #pragma unroll
        for (int r = 0; r < 8; ++r) {
            float mx = NEGV;
            #pragma unroll
            for (int t = 0; t < 8; ++t) mx = fmaxf(mx, (am[t] != 0.f) ? sc[r][t] : NEGV);
            mx = wred_max(mx);
            float sm = 0.f;
            #pragma unroll
            for (int t = 0; t < 8; ++t) {
                float e = (am[t] != 0.f) ? expf(sc[r][t] - mx) : 0.f;
                sc[r][t] = e; sm += e;
            }
            sm = wred_sum(sm);
            float s = (has != 0.f) ? 1.f / sm : 0.f;   // has=0 -> attn 0
            #pragma unroll
            for (int t = 0; t < 8; ++t) sc[r][t] *= s;
        }
        // ---- delta = attn @ V ----  lane owns d = 2l, 2l+1
        float d0a[8] = {0.f,0.f,0.f,0.f,0.f,0.f,0.f,0.f};
        float d1a[8] = {0.f,0.f,0.f,0.f,0.f,0.f,0.f,0.f};
        for (int t = 0; t < 8; ++t) {
            #pragma unroll
            for (int r = 0; r < 8; ++r) sh_a[R + r][l] = sc[r][t];
            stage_tile(Vb + (size_t)t * 64 * Dd, sh_t, tid);
            __syncthreads();
            for (int g = 0; g < 16; ++g) {
                float4 av[8];
                #pragma unroll
                for (int r = 0; r < 8; ++r) av[r] = *(const float4*)&sh_a[R + r][g * 4];
                #pragma unroll
                for (int j = 0; j < 4; ++j) {
                    int m = g * 4 + j;
                    float2 vv = *(const float2*)&sh_t[m][2 * l];
                    #pragma unroll
                    for (int r = 0; r < 8; ++r) {
                        float a = (j == 0) ? av[r].x : (j == 1) ? av[r].y : (j == 2) ? av[r].z : av[r].w;
                        d0a[r] += a * vv.x;
                        d1a[r] += a * vv.y;
                    }
                }
            }
            __syncthreads();
        }
        // ---- gate + y update (wave-local rows, lane-local d) ----
        #pragma unroll
        for (int r = 0; r < 8; ++r) {
            float y0 = sh_y[R + r][2 * l], y1 = sh_y[R + r][2 * l + 1];
            float z0 = wA * y0 + wB * d0a[r] + gB;
            float z1 = wA1 * y1 + wB1 * d1a[r] + gB1;
            float g0 = 1.f / (1.f + expf(-z0));
            float g1 = 1.f / (1.f + expf(-z1));
            sh_y[R + r][2 * l]     = y0 + g0 * d0a[r];
            sh_y[R + r][2 * l + 1] = y1 + g1 * d1a[r];
        }
        __syncthreads();
    }
    // ---- y_em[bs,n,b,:] = y - seed ----
    #pragma unroll
    for (int r = 0; r < 8; ++r) {
        int n = n0 + R + r;
        float2 sv = *(const float2*)(seed + ((size_t)bs * Nn + n) * Dd + 2 * l);
        float2 ov;
        ov.x = sh_y[R + r][2 * l]     - sv.x;
        ov.y = sh_y[R + r][2 * l + 1] - sv.y;
        *(float2*)(y_em + (((size_t)bs * Nn + n) * Bb + b) * Dd + 2 * l) = ov;
    }
}

// =====================================================================
// Kernel 2a: novelty path -> delta_em + per-n stats {nov, rmax, rsum}
// Same structure as k1 (single pass). Stats -> tail of pair's new_V region.
// =====================================================================
__global__ __launch_bounds__(256) void k2a_nov(
    const float* __restrict__ w_cand, const float* __restrict__ surprise,
    const float* __restrict__ emK, const float* __restrict__ emV, const float* __restrict__ emS,
    const float* __restrict__ rtau, const float* __restrict__ rtauw,
    float* __restrict__ delta_em, float* newV /* stats alias - no restrict */)
{
    const int bs = blockIdx.z, b = blockIdx.y, n0 = blockIdx.x * 32;
    const int tid = threadIdx.x;
    const int wv = tid >> 6, l = tid & 63;
    const int R = wv * 8;

    __shared__ float sh_y[32][Dd];        // w_norm tile
    __shared__ float sh_t[64][132];
    __shared__ float sh_a[32][64];

    const float tau  = softplusf(rtau[b])  + 0.1f;
    const float tauw = softplusf(rtauw[b]) + 0.1f;
    const float itau = 1.f / tau, itw = 1.f / tauw;
    const size_t pair = (size_t)(bs * Bb + b);
    float* stats = newV + pair * (size_t)(Mm * Dd) + 448 * Dd;

    float am[8]; bool anyact = false;
    #pragma unroll
    for (int t = 0; t < 8; ++t) {
        float s = emS[pair * Mm + t * 64 + l];
        am[t] = (s > 0.f) ? 1.f : 0.f;
        anyact = anyact || (s > 0.f);
    }
    const float has = __ballot(anyact) ? 1.f : 0.f;
    {
        const float4* s4 = (const float4*)(w_cand + ((size_t)bs * Nn + n0) * Dd);
        #pragma unroll
        for (int it = 0; it < 4; ++it) {
            int i = tid + it * 256;
            int row = i >> 5, c = i & 31;
            *(float4*)&sh_y[row][c * 4] = s4[i];
        }
    }
    __syncthreads();
    // normalize rows (wave-local rows, lane-local d)
    #pragma unroll
    for (int r = 0; r < 8; ++r) {
        float2 yv = *(const float2*)&sh_y[R + r][2 * l];
        float p = wred_sum(yv.x * yv.x + yv.y * yv.y);
        float inv = 1.f / fmaxf(sqrtf(p), 1e-12f);
        sh_y[R + r][2 * l]     = yv.x * inv;
        sh_y[R + r][2 * l + 1] = yv.y * inv;
    }
    __syncthreads();
    const float* Kb = emK + pair * Mm * Dd;
    const float* Vb = emV + pair * Mm * Dd;

    // ---- raw scores ----
    float sc[8][8];
    for (int t = 0; t < 8; ++t) {
        stage_tile(Kb + (size_t)t * 64 * Dd, sh_t, tid);
        __syncthreads();
        float acc[8] = {0.f,0.f,0.f,0.f,0.f,0.f,0.f,0.f};
        for (int c4 = 0; c4 < 32; ++c4) {
            float4 kv = *(const float4*)&sh_t[l][c4 * 4];
            #pragma unroll
            for (int r = 0; r < 8; ++r) {
                float4 yv = *(const float4*)&sh_y[R + r][c4 * 4];
                acc[r] += dot4(yv, kv);
            }
        }
        #pragma unroll
        for (int r = 0; r < 8; ++r) sc[r][t] = acc[r];   // raw dot
        __syncthreads();
    }
    // ---- dual softmax stats; sc <- nov_attn; route stats -> out-tail ----
    #pragma unroll
    for (int r = 0; r < 8; ++r) {
        float mx1 = NEGV, mx2 = NEGV;
        #pragma unroll
        for (int t = 0; t < 8; ++t) {
            bool a = (am[t] != 0.f);
            mx1 = fmaxf(mx1, a ? sc[r][t] * itau : NEGV);
            mx2 = fmaxf(mx2, a ? sc[r][t] * itw  : NEGV);
        }
        mx1 = wred_max(mx1); mx2 = wred_max(mx2);
        float s1 = 0.f, s2 = 0.f;
        #pragma unroll
        for (int t = 0; t < 8; ++t) {
            bool a = (am[t] != 0.f);
            float e1 = a ? expf(sc[r][t] * itau - mx1) : 0.f;
            float e2 = a ? expf(sc[r][t] * itw  - mx2) : 0.f;
            sc[r][t] = e1; s1 += e1; s2 += e2;
        }
        s1 = wred_sum(s1); s2 = wred_sum(s2);
        float s = (has != 0.f) ? 1.f / s1 : 0.f;
        #pragma unroll
        for (int t = 0; t < 8; ++t) sc[r][t] *= s;
        if (l == 0) {
            stats[1024 + n0 + R + r] = mx2;
            stats[2048 + n0 + R + r] = s2;
        }
    }
    // ---- recon = nov_attn @ V ----
    float d0a[8] = {0.f,0.f,0.f,0.f,0.f,0.f,0.f,0.f};
    float d1a[8] = {0.f,0.f,0.f,0.f,0.f,0.f,0.f,0.f};
    for (int t = 0; t < 8; ++t) {
        #pragma unroll
        for (int r = 0; r < 8; ++r) sh_a[R + r][l] = sc[r][t];
        stage_tile(Vb + (size_t)t * 64 * Dd, sh_t, tid);
        __syncthreads();
        for (int g = 0; g < 16; ++g) {
            float4 av[8];
            #pragma unroll
            for (int r = 0; r < 8; ++r) av[r] = *(const float4*)&sh_a[R + r][g * 4];
            #pragma unroll
            for (int j = 0; j < 4; ++j) {
                int m = g * 4 + j;
                float2 vv = *(const float2*)&sh_t[m][2 * l];
                #pragma unroll
                for (int r = 0; r < 8; ++r) {
                    float a = (j == 0) ? av[r].x : (j == 1) ? av[r].y : (j == 2) ? av[r].z : av[r].w;
                    d0a[r] += a * vv.x;
                    d1a[r] += a * vv.y;
                }
            }
        }
        __syncthreads();
    }
    // ---- novelty + delta_em ----
    #pragma unroll
    for (int r = 0; r < 8; ++r) {
        int n = n0 + R + r;
        float2 wc = *(const float2*)(w_cand + ((size_t)bs * Nn + n) * Dd + 2 * l);
        float dfx = wc.x - d0a[r], dfy = wc.y - d1a[r];
        float pe = wred_sum(dfx * dfx + dfy * dfy);
        float2 sp = *(const float2*)(surprise + ((size_t)bs * Nn + n) * Dd + 2 * l);
        float ps = wred_sum(sp.x * sp.x + sp.y * sp.y);
        float novl = 0.5f * sqrtf(ps) + 0.5f * sqrtf(pe);
        if (l == 0) stats[n] = novl;
        float2 ov; ov.x = novl * wc.x; ov.y = novl * wc.y;
        *(float2*)(delta_em + (((size_t)bs * Nn + n) * Bb + b) * Dd + 2 * l) = ov;
    }
}

// =====================================================================
// Kernel 2b: route recompute + update_K/V + new_K/V/age + S_pre (into newS)
// grid (#mtiles, B, BS), block 256.  Thread: ml = tid>>2 (m), dq = tid&3.
// Launched twice: mt_base=0 gridDim.x=7 (slots 0..447), then mt_base=7
// gridDim.x=1 (slots 448..511 — retires the stats region in its epilogue).
// =====================================================================
__global__ __launch_bounds__(256) void k2b_upd(
    const float* __restrict__ w_cand, const float* __restrict__ emK, const float* __restrict__ emV,
    const float* __restrict__ emS, const float* __restrict__ emAge,
    const float* __restrict__ g_em, const float* __restrict__ rtauw,
    float* __restrict__ newK, float* newV /* aliases stats - no restrict */,
    float* __restrict__ newAge, float* __restrict__ newS, int mt_base)
{
    const int bs = blockIdx.z, b = blockIdx.y, mt = mt_base + blockIdx.x;
    const int m0 = mt * 64;
    const int tid = threadIdx.x;
    const int ml = tid >> 2, dq = tid & 3, d0 = dq * 32;

    __shared__ float sh_wn[16][Dd];
    __shared__ float sh_nv[16], sh_rm[16], sh_rs[16], sh_nrm[16];
    __shared__ float sh_red[256];

    const float tauw = softplusf(rtauw[b]) + 0.1f;
    const float itw = 1.f / tauw;
    const float gv = g_em[bs * Bb + b];
    const size_t pair = (size_t)(bs * Bb + b);
    const float* stats = newV + pair * (size_t)(Mm * Dd) + 448 * Dd;
    const float actm = (emS[pair * Mm + m0 + ml] > 0.f) ? 1.f : 0.f;

    float kreg[32];
    {
        const float* Kr = emK + (pair * Mm + m0 + ml) * (size_t)Dd + d0;
        #pragma unroll
        for (int c = 0; c < 8; ++c) {
            float4 kv = *(const float4*)(Kr + c * 4);
            kreg[c * 4 + 0] = kv.x; kreg[c * 4 + 1] = kv.y;
            kreg[c * 4 + 2] = kv.z; kreg[c * 4 + 3] = kv.w;
        }
    }
    float uK[32], uV[32];
    #pragma unroll
    for (int j = 0; j < 32; ++j) { uK[j] = 0.f; uV[j] = 0.f; }
    float den = 0.f;

    for (int nt = 0; nt < Nn / 16; ++nt) {
        int nb = nt * 16;
        {
            const float4* s4 = (const float4*)(w_cand + ((size_t)bs * Nn + nb) * Dd);
            for (int i = tid; i < 16 * Dd / 4; i += 256) {
                int n = i >> 5, c = i & 31;
                *(float4*)&sh_wn[n][c * 4] = s4[i];
            }
        }
        if (tid < 16) {
            sh_nv[tid] = stats[nb + tid];
            sh_rm[tid] = stats[1024 + nb + tid];
            sh_rs[tid] = stats[2048 + nb + tid];
        }
        __syncthreads();
        {
            int n = tid >> 4, qq = tid & 15;
            float p = 0.f;
            #pragma unroll
            for (int e = 0; e < 8; ++e) { float v = sh_wn[n][qq * 8 + e]; p += v * v; }
            sh_red[tid] = p; __syncthreads();
            float tot = 0.f; int base = tid & ~15;
            #pragma unroll
            for (int j = 0; j < 16; ++j) tot += sh_red[base + j];
            __syncthreads();
            float nrm = fmaxf(sqrtf(tot), 1e-12f);
            float inv = 1.f / nrm;
            if (qq == 0) sh_nrm[n] = nrm;
            #pragma unroll
            for (int e = 0; e < 8; ++e) sh_wn[n][qq * 8 + e] *= inv;
        }
        __syncthreads();
        for (int nl = 0; nl < 16; ++nl) {
            const float* wn = &sh_wn[nl][d0];
            float p = 0.f;
            #pragma unroll
            for (int j = 0; j < 32; ++j) p += kreg[j] * wn[j];
            p += __shfl_xor(p, 1, 4);
            p += __shfl_xor(p, 2, 4);
            float val = (actm != 0.f) ? p * itw : NEGV;
            float wr = sh_nv[nl] * expf(val - sh_rm[nl]) / sh_rs[nl];
            den += wr;
            float wrv = wr * sh_nrm[nl];
            #pragma unroll
            for (int j = 0; j < 32; ++j) {
                float w = wn[j];
                uK[j] += wr * w;
                uV[j] += wrv * w;
            }
        }
        __syncthreads();
    }
    float invd = 1.f / fmaxf(den, 1e-8f);
    float ragg = den * (1.f / (float)Nn);
    float alpha = fminf(gv * ragg, 1.f);
    float oma = 1.f - alpha;
    float p = 0.f;
    #pragma unroll
    for (int j = 0; j < 32; ++j) { float u = uK[j] * invd; uK[j] = u; p += u * u; }
    p += __shfl_xor(p, 1, 4);
    p += __shfl_xor(p, 2, 4);
    float invn = 1.f / fmaxf(sqrtf(p), 1e-12f);

    float* Ko = newK + (pair * Mm + m0 + ml) * (size_t)Dd + d0;
    float* Vo = newV + (pair * Mm + m0 + ml) * (size_t)Dd + d0;
    const float* Vr = emV + (pair * Mm + m0 + ml) * (size_t)Dd + d0;
    #pragma unroll
    for (int c = 0; c < 8; ++c) {
        float4 ov;
        ov.x = oma * kreg[c * 4 + 0] + alpha * uK[c * 4 + 0] * invn;
        ov.y = oma * kreg[c * 4 + 1] + alpha * uK[c * 4 + 1] * invn;
        ov.z = oma * kreg[c * 4 + 2] + alpha * uK[c * 4 + 2] * invn;
        ov.w = oma * kreg[c * 4 + 3] + alpha * uK[c * 4 + 3] * invn;
        *(float4*)(Ko + c * 4) = ov;
    }
    #pragma unroll
    for (int c = 0; c < 8; ++c) {
        float4 vv = *(const float4*)(Vr + c * 4);
        float4 ov;
        ov.x = oma * vv.x + alpha * uV[c * 4 + 0] * invd;
        ov.y = oma * vv.y + alpha * uV[c * 4 + 1] * invd;
        ov.z = oma * vv.z + alpha * uV[c * 4 + 2] * invd;
        ov.w = oma * vv.w + alpha * uV[c * 4 + 3] * invd;
        *(float4*)(Vo + c * 4) = ov;
    }
    if (dq == 0) {
        float S = emS[pair * Mm + m0 + ml];
        float Sp = fminf(fmaxf(S + alpha, 0.f), 3.0f);
        newS[pair * Mm + m0 + ml] = Sp;
        float age = emAge[pair * Mm + m0 + ml];
        newAge[pair * Mm + m0 + ml] = age * oma;
    }
}

// =====================================================================
// Kernel 2c: budget rescale of new_S in place (f32)
// =====================================================================
__global__ __launch_bounds__(256) void k2c_scale(float* newS)
{
    const int p = blockIdx.x, tid = threadIdx.x;
    __shared__ float red[256];
    float v0 = newS[(size_t)p * Mm + tid];
    float v1 = newS[(size_t)p * Mm + 256 + tid];
    red[tid] = v0 + v1;
    __syncthreads();
    for (int s = 128; s > 0; s >>= 1) {
        if (tid < s) red[tid] += red[tid + s];
        __syncthreads();
    }
    float tot = red[0];
    float sc = fminf(1.f, 32.0f / fmaxf(tot, 1e-8f));
    newS[(size_t)p * Mm + tid]       = v0 * sc;
    newS[(size_t)p * Mm + 256 + tid] = v1 * sc;
}

// =====================================================================
extern "C" void kernel_launch(void* const* d_in, const int* in_sizes, int n_in,
                              void* d_out, int out_size, void* d_ws, size_t ws_size,
                              hipStream_t stream)
{
    const float* seed     = (const float*)d_in[0];
    const float* w_cand   = (const float*)d_in[1];
    const float* surprise = (const float*)d_in[2];
    const float* g_em     = (const float*)d_in[3];
    const float* emK      = (const float*)d_in[4];
    const float* emV      = (const float*)d_in[5];
    const float* emS      = (const float*)d_in[6];
    const float* emAge    = (const float*)d_in[7];
    const float* w1       = (const float*)d_in[8];
    const float* w2       = (const float*)d_in[9];
    const float* gb       = (const float*)d_in[10];
    const float* rtau     = (const float*)d_in[11];
    const float* rtauw    = (const float*)d_in[12];

    float* out = (float*)d_out;
    float* y_em     = out;                            // (BS,N,B,D)  8388608
    float* delta_em = out + (size_t)8388608;          // (BS,N,B,D)  8388608
    float* newK     = out + (size_t)16777216;         // (BS,B,M,D)  4194304
    float* newV     = out + (size_t)20971520;         // (BS,B,M,D)  4194304
    float* newS     = out + (size_t)25165824;         // (BS,B,M)    32768
    float* newAge   = out + (size_t)25198592;         // (BS,B,M)    32768
    (void)d_ws; (void)ws_size;

    dim3 blk(256);
    dim3 g1(Nn / 32, Bb, BSz);          // 32 x 8 x 8
    k1_attn<<<g1, blk, 0, stream>>>(seed, emK, emV, emS, w1, w2, gb, rtau, y_em);
    k2a_nov<<<g1, blk, 0, stream>>>(w_cand, surprise, emK, emV, emS, rtau, rtauw,
                                    delta_em, newV);
    k2b_upd<<<dim3(7, Bb, BSz), blk, 0, stream>>>(w_cand, emK, emV, emS, emAge, g_em, rtauw,
                                                  newK, newV, newAge, newS, 0);
    k2b_upd<<<dim3(1, Bb, BSz), blk, 0, stream>>>(w_cand, emK, emV, emS, emAge, g_em, rtauw,
                                                  newK, newV, newAge, newS, 7);
    k2c_scale<<<dim3(64), blk, 0, stream>>>(newS);
}